// Round 9
// baseline (825.413 us; speedup 1.0000x reference)
//
#include <hip/hip_runtime.h>
#include <hip/hip_bf16.h>
#include <stdint.h>

#define D_MODEL 1024
#define D_FF    4096
#define N_EXP   8
#define TOPK    2
#define NTOK    8192
#define NASSIGN (NTOK*TOPK)

#define BM 128
#define BN 128
#define BK 64
#define THREADS 256

typedef __bf16 bf16_t;
typedef __attribute__((ext_vector_type(8))) bf16_t bf16x8;
typedef __attribute__((ext_vector_type(4))) float f32x4;

__device__ __forceinline__ unsigned short f2bf(float f) {
    bf16_t b = (bf16_t)f;
    return __builtin_bit_cast(unsigned short, b);
}

__device__ __forceinline__ void gload_lds16(const void* g, void* l) {
    __builtin_amdgcn_global_load_lds(
        (const __attribute__((address_space(1))) void*)g,
        (__attribute__((address_space(3))) void*)l, 16, 0, 0);
}

// ---------------- fp32 -> bf16 convert (weights) ----------------
__global__ void cvt_bf16_kernel(const float* __restrict__ in, unsigned short* __restrict__ outp, int n) {
    int stride = gridDim.x * blockDim.x;
    for (int i = blockIdx.x * blockDim.x + threadIdx.x; i < n / 4; i += stride) {
        float4 v = ((const float4*)in)[i];
        ushort4 o;
        o.x = f2bf(v.x); o.y = f2bf(v.y); o.z = f2bf(v.z); o.w = f2bf(v.w);
        ((ushort4*)outp)[i] = o;
    }
}

// ---------------- router (fused: also emits x in bf16) ----------------
__global__ __launch_bounds__(64) void router_kernel(
        const float* __restrict__ x, const float* __restrict__ gw,
        int* __restrict__ counts, int* __restrict__ ltok, float* __restrict__ lw,
        unsigned short* __restrict__ xb) {
    int n = blockIdx.x;
    int lane = threadIdx.x;
    const float* xr = x + (size_t)n * D_MODEL;
    unsigned short* xbr = xb + (size_t)n * D_MODEL;
    float acc[N_EXP];
    #pragma unroll
    for (int e = 0; e < N_EXP; e++) acc[e] = 0.f;
    #pragma unroll
    for (int i = 0; i < 4; i++) {
        int j = lane + i * 64;                  // float4 index
        float4 v = ((const float4*)xr)[j];
        ushort4 o;
        o.x = f2bf(v.x); o.y = f2bf(v.y); o.z = f2bf(v.z); o.w = f2bf(v.w);
        ((ushort4*)xbr)[j] = o;
        int d = j * 4;
        #pragma unroll
        for (int e = 0; e < N_EXP; e++) {
            const float* g = gw + e * D_MODEL + d;
            acc[e] += v.x * g[0] + v.y * g[1] + v.z * g[2] + v.w * g[3];
        }
    }
    #pragma unroll
    for (int e = 0; e < N_EXP; e++) {
        #pragma unroll
        for (int off = 32; off > 0; off >>= 1)
            acc[e] += __shfl_down(acc[e], off);
    }
    if (lane == 0) {
        float mx = acc[0];
        #pragma unroll
        for (int e = 1; e < N_EXP; e++) mx = fmaxf(mx, acc[e]);
        float p[N_EXP];
        float s = 0.f;
        #pragma unroll
        for (int e = 0; e < N_EXP; e++) { p[e] = expf(acc[e] - mx); s += p[e]; }
        float inv = 1.f / s;
        #pragma unroll
        for (int e = 0; e < N_EXP; e++) p[e] *= inv;
        int i0 = 0;
        #pragma unroll
        for (int e = 1; e < N_EXP; e++) if (p[e] > p[i0]) i0 = e;
        int i1 = (i0 == 0) ? 1 : 0;
        #pragma unroll
        for (int e = 0; e < N_EXP; e++) if (e != i0 && p[e] > p[i1]) i1 = e;
        float s2 = p[i0] + p[i1] + 1e-9f;
        float w0 = p[i0] / s2, w1 = p[i1] / s2;
        int pos0 = atomicAdd(&counts[i0], 1);
        ltok[i0 * NTOK + pos0] = n; lw[i0 * NTOK + pos0] = w0;
        int pos1 = atomicAdd(&counts[i1], 1);
        ltok[i1 * NTOK + pos1] = n; lw[i1 * NTOK + pos1] = w1;
    }
}

// ---------------- exclusive scan over 8 expert counts ----------------
__global__ void scan_kernel(const int* __restrict__ counts, int* __restrict__ offs) {
    if (threadIdx.x == 0 && blockIdx.x == 0) {
        int s = 0;
        for (int e = 0; e < N_EXP; e++) { offs[e] = s; s += counts[e]; }
    }
}

// =====================================================================
// r9: r4 base (BK=64 XOR-swizzle, conflicts=0; expert->XCD; 4 blocks/CU)
// + the T3+T4 MINIMUM 2-phase recipe, implemented exactly for the first
// time: stage(next) issued at ITER TOP (before ds_read+MFMA, so DMA
// latency hides under the whole compute phase), ONE vmcnt(0)+barrier at
// iter end (not per sub-phase). Correctness: waves' ds_reads of buf
// cur^1 retired before the PREVIOUS iter's end barrier (lgkmcnt(0)
// precedes it), so staging cur^1 after that barrier is race-free; the
// end-of-iter vmcnt(0)+barrier publishes the staged buffer to all waves.
// ks-split fragment reads cap VGPR ~110 -> __launch_bounds__(256,4).
// =====================================================================

#define GEMM_PIPE_LOOP(NT_)                                                    \
    stage(0, 0);                                                               \
    asm volatile("s_waitcnt vmcnt(0)" ::: "memory");                           \
    __builtin_amdgcn_sched_barrier(0);                                         \
    __builtin_amdgcn_s_barrier();                                              \
    __builtin_amdgcn_sched_barrier(0);                                         \
    for (int tt = 0; tt < (NT_); ++tt) {                                       \
        int cur = tt & 1;                                                      \
        if (tt + 1 < (NT_)) stage(cur ^ 1, (tt + 1) * BK);                     \
        const char* Ab = As_b + cur * 16384;                                   \
        const char* Bb = Bs_b + cur * 16384;                                   \
        _Pragma("unroll")                                                      \
        for (int ks = 0; ks < 2; ks++) {                                       \
            bf16x8 af[4], bf[4];                                               \
            _Pragma("unroll")                                                  \
            for (int m = 0; m < 4; m++)                                        \
                af[m] = *(const bf16x8*)(Ab + (arow_base + m * 16) * 128 + ch[ks]); \
            _Pragma("unroll")                                                  \
            for (int n = 0; n < 4; n++)                                        \
                bf[n] = *(const bf16x8*)(Bb + (brow_base + n * 16) * 128 + ch[ks]); \
            asm volatile("s_waitcnt lgkmcnt(0)" ::: "memory");                 \
            __builtin_amdgcn_sched_barrier(0);                                 \
            __builtin_amdgcn_s_setprio(1);                                     \
            _Pragma("unroll")                                                  \
            for (int m = 0; m < 4; m++)                                        \
                _Pragma("unroll")                                              \
                for (int n = 0; n < 4; n++)                                    \
                    acc[m][n] = __builtin_amdgcn_mfma_f32_16x16x32_bf16(       \
                        af[m], bf[n], acc[m][n], 0, 0, 0);                     \
            __builtin_amdgcn_s_setprio(0);                                     \
        }                                                                      \
        __builtin_amdgcn_sched_barrier(0);                                     \
        asm volatile("s_waitcnt vmcnt(0)" ::: "memory");                       \
        __builtin_amdgcn_sched_barrier(0);                                     \
        __builtin_amdgcn_s_barrier();                                          \
        __builtin_amdgcn_sched_barrier(0);                                     \
    }

// GEMM1: h = relu(X_gathered @ W1[e]^T + b1[e])
__global__ __launch_bounds__(THREADS, 4) void gemm1_kernel(
        const unsigned short* __restrict__ xb, const unsigned short* __restrict__ w1b,
        const float* __restrict__ b1,
        const int* __restrict__ counts, const int* __restrict__ offs,
        const int* __restrict__ ltok,
        unsigned short* __restrict__ hb) {
    const int NTM = NTOK / BM;   // 64 (worst case)
    int b = blockIdx.x;
    int e = b & 7;               // expert -> XCD
    int idx = b >> 3;
    int nt = idx / NTM;          // W-panel major
    int mt = idx % NTM;
    int cnt = counts[e];
    if (mt * BM >= cnt) return;

    __shared__ __align__(16) unsigned short As[2][BM * BK];   // 2 x 16 KB
    __shared__ __align__(16) unsigned short Bs[2][BN * BK];   // 2 x 16 KB

    int t = threadIdx.x;
    int lane = t & 63, w = t >> 6;     // 4 waves
    int wr = w >> 1, wc = w & 1;       // 2 x 2

    // staging: thread -> rows (t>>3)+j*32, slot t&7, source chunk slot^(row&7)
    int srow = t >> 3;                       // 0..31
    int schunk = (t & 7) ^ (srow & 7);
    const unsigned short* aptr[4];
    const unsigned short* bptr[4];
    #pragma unroll
    for (int j = 0; j < 4; j++) {
        int rr = srow + j * 32;
        int slot = mt * BM + rr;
        int cs = slot < cnt ? slot : (cnt - 1);
        int tok = ltok[e * NTOK + cs];
        aptr[j] = xb + (size_t)tok * D_MODEL + schunk * 8;
        bptr[j] = w1b + ((size_t)e * D_FF + nt * BN + rr) * D_MODEL + schunk * 8;
    }
    char* As_b = (char*)As;
    char* Bs_b = (char*)Bs;

    auto stage = [&](int buf, int k0) {
        #pragma unroll
        for (int j = 0; j < 4; j++) {
            gload_lds16(aptr[j] + k0, As_b + buf * 16384 + j * 4096 + t * 16);
            gload_lds16(bptr[j] + k0, Bs_b + buf * 16384 + j * 4096 + t * 16);
        }
    };

    int arow_base = wr * 64 + (lane & 15);
    int brow_base = wc * 64 + (lane & 15);
    int ch[2];
    #pragma unroll
    for (int ks = 0; ks < 2; ks++)
        ch[ks] = ((ks * 4 + (lane >> 4)) ^ (lane & 7)) << 4;

    f32x4 acc[4][4];
    #pragma unroll
    for (int m = 0; m < 4; m++)
        #pragma unroll
        for (int n = 0; n < 4; n++)
            acc[m][n] = (f32x4){0.f, 0.f, 0.f, 0.f};

    const int NT = D_MODEL / BK;   // 16
    GEMM_PIPE_LOOP(NT)

    int hbase = offs[e];
    float biasv[4];
    #pragma unroll
    for (int n = 0; n < 4; ++n)
        biasv[n] = b1[e * D_FF + nt * BN + wc * 64 + n * 16 + (lane & 15)];
    #pragma unroll
    for (int m = 0; m < 4; ++m) {
        int s0 = mt * BM + wr * 64 + m * 16 + (lane >> 4) * 4;
        #pragma unroll
        for (int rq = 0; rq < 4; ++rq) {
            int s = s0 + rq;
            if (s < cnt) {
                size_t rowoff = (size_t)(hbase + s) * D_FF + nt * BN + wc * 64 + (lane & 15);
                #pragma unroll
                for (int n = 0; n < 4; ++n) {
                    float v = fmaxf(acc[m][n][rq] + biasv[n], 0.f);
                    hb[rowoff + n * 16] = f2bf(v);
                }
            }
        }
    }
}

// GEMM2: y = h @ W2[e]^T + b2[e]; weighted atomic scatter to out
__global__ __launch_bounds__(THREADS, 4) void gemm2_kernel(
        const unsigned short* __restrict__ hb, const unsigned short* __restrict__ w2b,
        const float* __restrict__ b2,
        const int* __restrict__ counts, const int* __restrict__ offs,
        const int* __restrict__ ltok, const float* __restrict__ lw,
        float* __restrict__ out) {
    const int NTM = NTOK / BM;     // 64
    int b = blockIdx.x;
    int e = b & 7;
    int idx = b >> 3;
    int nt = idx / NTM;
    int mt = idx % NTM;
    int cnt = counts[e];
    if (mt * BM >= cnt) return;
    int hbase = offs[e];

    __shared__ __align__(16) unsigned short As[2][BM * BK];
    __shared__ __align__(16) unsigned short Bs[2][BN * BK];

    int t = threadIdx.x;
    int lane = t & 63, w = t >> 6;
    int wr = w >> 1, wc = w & 1;

    int srow = t >> 3;
    int schunk = (t & 7) ^ (srow & 7);
    const unsigned short* aptr[4];
    const unsigned short* bptr[4];
    #pragma unroll
    for (int j = 0; j < 4; j++) {
        int rr = srow + j * 32;
        int slot = mt * BM + rr;
        int cs = slot < cnt ? slot : (cnt - 1);
        aptr[j] = hb + (size_t)(hbase + cs) * D_FF + schunk * 8;
        bptr[j] = w2b + ((size_t)e * D_MODEL + nt * BN + rr) * D_FF + schunk * 8;
    }
    char* As_b = (char*)As;
    char* Bs_b = (char*)Bs;

    auto stage = [&](int buf, int k0) {
        #pragma unroll
        for (int j = 0; j < 4; j++) {
            gload_lds16(aptr[j] + k0, As_b + buf * 16384 + j * 4096 + t * 16);
            gload_lds16(bptr[j] + k0, Bs_b + buf * 16384 + j * 4096 + t * 16);
        }
    };

    int arow_base = wr * 64 + (lane & 15);
    int brow_base = wc * 64 + (lane & 15);
    int ch[2];
    #pragma unroll
    for (int ks = 0; ks < 2; ks++)
        ch[ks] = ((ks * 4 + (lane >> 4)) ^ (lane & 7)) << 4;

    f32x4 acc[4][4];
    #pragma unroll
    for (int m = 0; m < 4; m++)
        #pragma unroll
        for (int n = 0; n < 4; n++)
            acc[m][n] = (f32x4){0.f, 0.f, 0.f, 0.f};

    const int NT = D_FF / BK;   // 64
    GEMM_PIPE_LOOP(NT)

    int lbase = e * NTOK;
    float biasv[4];
    #pragma unroll
    for (int n = 0; n < 4; ++n)
        biasv[n] = b2[e * D_MODEL + nt * BN + wc * 64 + n * 16 + (lane & 15)];
    #pragma unroll
    for (int m = 0; m < 4; ++m) {
        int s0 = mt * BM + wr * 64 + m * 16 + (lane >> 4) * 4;
        #pragma unroll
        for (int rq = 0; rq < 4; ++rq) {
            int s = s0 + rq;
            if (s >= cnt) continue;
            int tok = ltok[lbase + s];
            float wgt = lw[lbase + s];
            float* orow = out + (size_t)tok * D_MODEL + nt * BN + wc * 64 + (lane & 15);
            #pragma unroll
            for (int n = 0; n < 4; ++n)
                atomicAdd(orow + n * 16, wgt * (acc[m][n][rq] + biasv[n]));
        }
    }
}

extern "C" void kernel_launch(void* const* d_in, const int* in_sizes, int n_in,
                              void* d_out, int out_size, void* d_ws, size_t ws_size,
                              hipStream_t stream) {
    const float* x  = (const float*)d_in[0];
    const float* gw = (const float*)d_in[1];
    const float* W1 = (const float*)d_in[2];
    const float* b1 = (const float*)d_in[3];
    const float* W2 = (const float*)d_in[4];
    const float* b2 = (const float*)d_in[5];
    float* out = (float*)d_out;

    char* ws = (char*)d_ws;
    size_t off = 0;
    auto alloc = [&](size_t bytes) -> char* {
        char* p = ws + off;
        off += (bytes + 255) & ~(size_t)255;
        return p;
    };
    unsigned short* xb  = (unsigned short*)alloc((size_t)NTOK * D_MODEL * 2);
    unsigned short* w1b = (unsigned short*)alloc((size_t)N_EXP * D_FF * D_MODEL * 2);
    unsigned short* w2b = (unsigned short*)alloc((size_t)N_EXP * D_MODEL * D_FF * 2);
    unsigned short* hb  = (unsigned short*)alloc((size_t)NASSIGN * D_FF * 2);
    int*   counts = (int*)alloc(256);
    int*   offs   = (int*)alloc(256);
    int*   ltok   = (int*)alloc((size_t)N_EXP * NTOK * 4);
    float* lw     = (float*)alloc((size_t)N_EXP * NTOK * 4);

    hipMemsetAsync(out, 0, (size_t)out_size * 4, stream);
    hipMemsetAsync(counts, 0, 256, stream);
    cvt_bf16_kernel<<<4096, 256, 0, stream>>>(W1, w1b, N_EXP * D_FF * D_MODEL);
    cvt_bf16_kernel<<<4096, 256, 0, stream>>>(W2, w2b, N_EXP * D_MODEL * D_FF);
    router_kernel<<<NTOK, 64, 0, stream>>>(x, gw, counts, ltok, lw, xb);
    scan_kernel<<<1, 64, 0, stream>>>(counts, offs);
    gemm1_kernel<<<N_EXP * (NTOK / BM) * (D_FF / BN), THREADS, 0, stream>>>(
        xb, w1b, b1, counts, offs, ltok, hb);
    gemm2_kernel<<<N_EXP * (NTOK / BM) * (D_MODEL / BN), THREADS, 0, stream>>>(
        hb, w2b, b2, counts, offs, ltok, lw, out);
}

// Round 10
// 817.709 us; speedup vs baseline: 1.0094x; 1.0094x over previous
//
#include <hip/hip_runtime.h>
#include <hip/hip_bf16.h>
#include <stdint.h>

#define D_MODEL 1024
#define D_FF    4096
#define N_EXP   8
#define TOPK    2
#define NTOK    8192
#define NASSIGN (NTOK*TOPK)

#define BM 128
#define BN 128
#define BK 64
#define THREADS 256

typedef __bf16 bf16_t;
typedef __attribute__((ext_vector_type(8))) bf16_t bf16x8;
typedef __attribute__((ext_vector_type(4))) float f32x4;

__device__ __forceinline__ unsigned short f2bf(float f) {
    bf16_t b = (bf16_t)f;
    return __builtin_bit_cast(unsigned short, b);
}

__device__ __forceinline__ void gload_lds16(const void* g, void* l) {
    __builtin_amdgcn_global_load_lds(
        (const __attribute__((address_space(1))) void*)g,
        (__attribute__((address_space(3))) void*)l, 16, 0, 0);
}

// ---------------- fp32 -> bf16 convert (weights) ----------------
__global__ void cvt_bf16_kernel(const float* __restrict__ in, unsigned short* __restrict__ outp, int n) {
    int stride = gridDim.x * blockDim.x;
    for (int i = blockIdx.x * blockDim.x + threadIdx.x; i < n / 4; i += stride) {
        float4 v = ((const float4*)in)[i];
        ushort4 o;
        o.x = f2bf(v.x); o.y = f2bf(v.y); o.z = f2bf(v.z); o.w = f2bf(v.w);
        ((ushort4*)outp)[i] = o;
    }
}

// ---------------- router (fused: also emits x in bf16) ----------------
__global__ __launch_bounds__(64) void router_kernel(
        const float* __restrict__ x, const float* __restrict__ gw,
        int* __restrict__ counts, int* __restrict__ ltok, float* __restrict__ lw,
        unsigned short* __restrict__ xb) {
    int n = blockIdx.x;
    int lane = threadIdx.x;
    const float* xr = x + (size_t)n * D_MODEL;
    unsigned short* xbr = xb + (size_t)n * D_MODEL;
    float acc[N_EXP];
    #pragma unroll
    for (int e = 0; e < N_EXP; e++) acc[e] = 0.f;
    #pragma unroll
    for (int i = 0; i < 4; i++) {
        int j = lane + i * 64;                  // float4 index
        float4 v = ((const float4*)xr)[j];
        ushort4 o;
        o.x = f2bf(v.x); o.y = f2bf(v.y); o.z = f2bf(v.z); o.w = f2bf(v.w);
        ((ushort4*)xbr)[j] = o;
        int d = j * 4;
        #pragma unroll
        for (int e = 0; e < N_EXP; e++) {
            const float* g = gw + e * D_MODEL + d;
            acc[e] += v.x * g[0] + v.y * g[1] + v.z * g[2] + v.w * g[3];
        }
    }
    #pragma unroll
    for (int e = 0; e < N_EXP; e++) {
        #pragma unroll
        for (int off = 32; off > 0; off >>= 1)
            acc[e] += __shfl_down(acc[e], off);
    }
    if (lane == 0) {
        float mx = acc[0];
        #pragma unroll
        for (int e = 1; e < N_EXP; e++) mx = fmaxf(mx, acc[e]);
        float p[N_EXP];
        float s = 0.f;
        #pragma unroll
        for (int e = 0; e < N_EXP; e++) { p[e] = expf(acc[e] - mx); s += p[e]; }
        float inv = 1.f / s;
        #pragma unroll
        for (int e = 0; e < N_EXP; e++) p[e] *= inv;
        int i0 = 0;
        #pragma unroll
        for (int e = 1; e < N_EXP; e++) if (p[e] > p[i0]) i0 = e;
        int i1 = (i0 == 0) ? 1 : 0;
        #pragma unroll
        for (int e = 0; e < N_EXP; e++) if (e != i0 && p[e] > p[i1]) i1 = e;
        float s2 = p[i0] + p[i1] + 1e-9f;
        float w0 = p[i0] / s2, w1 = p[i1] / s2;
        int pos0 = atomicAdd(&counts[i0], 1);
        ltok[i0 * NTOK + pos0] = n; lw[i0 * NTOK + pos0] = w0;
        int pos1 = atomicAdd(&counts[i1], 1);
        ltok[i1 * NTOK + pos1] = n; lw[i1 * NTOK + pos1] = w1;
    }
}

// ---------------- exclusive scan over 8 expert counts ----------------
__global__ void scan_kernel(const int* __restrict__ counts, int* __restrict__ offs) {
    if (threadIdx.x == 0 && blockIdx.x == 0) {
        int s = 0;
        for (int e = 0; e < N_EXP; e++) { offs[e] = s; s += counts[e]; }
    }
}

// =====================================================================
// r10 = r4 EXACTLY (best measured: gemm2 225us) + one lever:
// __launch_bounds__(256,4) instead of 3. LDS 32KB/block allows 5
// blocks/CU; gemm2's active grid is exactly 4 blocks/CU -> cap 4 makes
// the WHOLE gemm2 co-resident (no tail; max m114 inter-block overlap,
// the only lever that has moved this kernel). r8/r9 dbuf lesson: 64KB
// LDS halves residency and loses regardless of schedule quality.
// =====================================================================

// GEMM1: h = relu(X_gathered @ W1[e]^T + b1[e])
__global__ __launch_bounds__(THREADS, 4) void gemm1_kernel(
        const unsigned short* __restrict__ xb, const unsigned short* __restrict__ w1b,
        const float* __restrict__ b1,
        const int* __restrict__ counts, const int* __restrict__ offs,
        const int* __restrict__ ltok,
        unsigned short* __restrict__ hb) {
    const int NTM = NTOK / BM;   // 64 (worst case)
    int b = blockIdx.x;
    int e = b & 7;               // expert -> XCD
    int idx = b >> 3;
    int nt = idx / NTM;          // W-panel major: co-resident blocks share nt
    int mt = idx % NTM;
    int cnt = counts[e];
    if (mt * BM >= cnt) return;

    __shared__ __align__(16) unsigned short As[BM * BK];   // 16 KB
    __shared__ __align__(16) unsigned short Bs[BN * BK];   // 16 KB

    int t = threadIdx.x;
    int lane = t & 63, w = t >> 6;     // 4 waves
    int wr = w >> 1, wc = w & 1;       // 2 x 2

    // staging: thread -> row (t>>3)+j*32, slot t&7; source chunk = slot^(row&7)
    int srow = t >> 3;                       // 0..31
    int schunk = (t & 7) ^ (srow & 7);
    const unsigned short* aptr[4];
    const unsigned short* bptr[4];
    #pragma unroll
    for (int j = 0; j < 4; j++) {
        int rr = srow + j * 32;
        int slot = mt * BM + rr;
        int cs = slot < cnt ? slot : (cnt - 1);
        int tok = ltok[e * NTOK + cs];
        aptr[j] = xb + (size_t)tok * D_MODEL + schunk * 8;
        bptr[j] = w1b + ((size_t)e * D_FF + nt * BN + rr) * D_MODEL + schunk * 8;
    }
    char* As_b = (char*)As;
    char* Bs_b = (char*)Bs;

    int arow_base = wr * 64 + (lane & 15);
    int brow_base = wc * 64 + (lane & 15);
    int ch[2];
    #pragma unroll
    for (int ks = 0; ks < 2; ks++)
        ch[ks] = ((ks * 4 + (lane >> 4)) ^ (lane & 7)) << 4;

    f32x4 acc[4][4];
    #pragma unroll
    for (int m = 0; m < 4; m++)
        #pragma unroll
        for (int n = 0; n < 4; n++)
            acc[m][n] = (f32x4){0.f, 0.f, 0.f, 0.f};

    for (int k0 = 0; k0 < D_MODEL; k0 += BK) {
        #pragma unroll
        for (int j = 0; j < 4; j++) {
            gload_lds16(aptr[j] + k0, As_b + j * 4096 + t * 16);
            gload_lds16(bptr[j] + k0, Bs_b + j * 4096 + t * 16);
        }
        __syncthreads();
        bf16x8 af[2][4], bf[2][4];
        #pragma unroll
        for (int ks = 0; ks < 2; ks++) {
            #pragma unroll
            for (int m = 0; m < 4; m++)
                af[ks][m] = *(const bf16x8*)(As_b + (size_t)(arow_base + m * 16) * 128 + ch[ks]);
            #pragma unroll
            for (int n = 0; n < 4; n++)
                bf[ks][n] = *(const bf16x8*)(Bs_b + (size_t)(brow_base + n * 16) * 128 + ch[ks]);
        }
        #pragma unroll
        for (int ks = 0; ks < 2; ks++)
            #pragma unroll
            for (int m = 0; m < 4; m++)
                #pragma unroll
                for (int n = 0; n < 4; n++)
                    acc[m][n] = __builtin_amdgcn_mfma_f32_16x16x32_bf16(af[ks][m], bf[ks][n], acc[m][n], 0, 0, 0);
        __syncthreads();
    }

    // epilogue: relu + bias, store bf16
    int hbase = offs[e];
    float biasv[4];
    #pragma unroll
    for (int n = 0; n < 4; ++n)
        biasv[n] = b1[e * D_FF + nt * BN + wc * 64 + n * 16 + (lane & 15)];
    #pragma unroll
    for (int m = 0; m < 4; ++m) {
        int s0 = mt * BM + wr * 64 + m * 16 + (lane >> 4) * 4;
        #pragma unroll
        for (int rq = 0; rq < 4; ++rq) {
            int s = s0 + rq;
            if (s < cnt) {
                size_t rowoff = (size_t)(hbase + s) * D_FF + nt * BN + wc * 64 + (lane & 15);
                #pragma unroll
                for (int n = 0; n < 4; ++n) {
                    float v = fmaxf(acc[m][n][rq] + biasv[n], 0.f);
                    hb[rowoff + n * 16] = f2bf(v);
                }
            }
        }
    }
}

// GEMM2: y = h @ W2[e]^T + b2[e]; weighted atomic scatter to out
__global__ __launch_bounds__(THREADS, 4) void gemm2_kernel(
        const unsigned short* __restrict__ hb, const unsigned short* __restrict__ w2b,
        const float* __restrict__ b2,
        const int* __restrict__ counts, const int* __restrict__ offs,
        const int* __restrict__ ltok, const float* __restrict__ lw,
        float* __restrict__ out) {
    const int NTM = NTOK / BM;     // 64
    int b = blockIdx.x;
    int e = b & 7;
    int idx = b >> 3;
    int nt = idx / NTM;
    int mt = idx % NTM;
    int cnt = counts[e];
    if (mt * BM >= cnt) return;
    int hbase = offs[e];

    __shared__ __align__(16) unsigned short As[BM * BK];
    __shared__ __align__(16) unsigned short Bs[BN * BK];

    int t = threadIdx.x;
    int lane = t & 63, w = t >> 6;
    int wr = w >> 1, wc = w & 1;

    int srow = t >> 3;
    int schunk = (t & 7) ^ (srow & 7);
    const unsigned short* aptr[4];
    const unsigned short* bptr[4];
    #pragma unroll
    for (int j = 0; j < 4; j++) {
        int rr = srow + j * 32;
        int slot = mt * BM + rr;
        int cs = slot < cnt ? slot : (cnt - 1);
        aptr[j] = hb + (size_t)(hbase + cs) * D_FF + schunk * 8;
        bptr[j] = w2b + ((size_t)e * D_MODEL + nt * BN + rr) * D_FF + schunk * 8;
    }
    char* As_b = (char*)As;
    char* Bs_b = (char*)Bs;

    int arow_base = wr * 64 + (lane & 15);
    int brow_base = wc * 64 + (lane & 15);
    int ch[2];
    #pragma unroll
    for (int ks = 0; ks < 2; ks++)
        ch[ks] = ((ks * 4 + (lane >> 4)) ^ (lane & 7)) << 4;

    f32x4 acc[4][4];
    #pragma unroll
    for (int m = 0; m < 4; m++)
        #pragma unroll
        for (int n = 0; n < 4; n++)
            acc[m][n] = (f32x4){0.f, 0.f, 0.f, 0.f};

    for (int k0 = 0; k0 < D_FF; k0 += BK) {
        #pragma unroll
        for (int j = 0; j < 4; j++) {
            gload_lds16(aptr[j] + k0, As_b + j * 4096 + t * 16);
            gload_lds16(bptr[j] + k0, Bs_b + j * 4096 + t * 16);
        }
        __syncthreads();
        bf16x8 af[2][4], bf[2][4];
        #pragma unroll
        for (int ks = 0; ks < 2; ks++) {
            #pragma unroll
            for (int m = 0; m < 4; m++)
                af[ks][m] = *(const bf16x8*)(As_b + (size_t)(arow_base + m * 16) * 128 + ch[ks]);
            #pragma unroll
            for (int n = 0; n < 4; n++)
                bf[ks][n] = *(const bf16x8*)(Bs_b + (size_t)(brow_base + n * 16) * 128 + ch[ks]);
        }
        #pragma unroll
        for (int ks = 0; ks < 2; ks++)
            #pragma unroll
            for (int m = 0; m < 4; m++)
                #pragma unroll
                for (int n = 0; n < 4; n++)
                    acc[m][n] = __builtin_amdgcn_mfma_f32_16x16x32_bf16(af[ks][m], bf[ks][n], acc[m][n], 0, 0, 0);
        __syncthreads();
    }

    // epilogue: weighted atomic scatter
    int lbase = e * NTOK;
    float biasv[4];
    #pragma unroll
    for (int n = 0; n < 4; ++n)
        biasv[n] = b2[e * D_MODEL + nt * BN + wc * 64 + n * 16 + (lane & 15)];
    #pragma unroll
    for (int m = 0; m < 4; ++m) {
        int s0 = mt * BM + wr * 64 + m * 16 + (lane >> 4) * 4;
        #pragma unroll
        for (int rq = 0; rq < 4; ++rq) {
            int s = s0 + rq;
            if (s >= cnt) continue;
            int tok = ltok[lbase + s];
            float wgt = lw[lbase + s];
            float* orow = out + (size_t)tok * D_MODEL + nt * BN + wc * 64 + (lane & 15);
            #pragma unroll
            for (int n = 0; n < 4; ++n)
                atomicAdd(orow + n * 16, wgt * (acc[m][n][rq] + biasv[n]));
        }
    }
}

extern "C" void kernel_launch(void* const* d_in, const int* in_sizes, int n_in,
                              void* d_out, int out_size, void* d_ws, size_t ws_size,
                              hipStream_t stream) {
    const float* x  = (const float*)d_in[0];
    const float* gw = (const float*)d_in[1];
    const float* W1 = (const float*)d_in[2];
    const float* b1 = (const float*)d_in[3];
    const float* W2 = (const float*)d_in[4];
    const float* b2 = (const float*)d_in[5];
    float* out = (float*)d_out;

    char* ws = (char*)d_ws;
    size_t off = 0;
    auto alloc = [&](size_t bytes) -> char* {
        char* p = ws + off;
        off += (bytes + 255) & ~(size_t)255;
        return p;
    };
    unsigned short* xb  = (unsigned short*)alloc((size_t)NTOK * D_MODEL * 2);
    unsigned short* w1b = (unsigned short*)alloc((size_t)N_EXP * D_FF * D_MODEL * 2);
    unsigned short* w2b = (unsigned short*)alloc((size_t)N_EXP * D_MODEL * D_FF * 2);
    unsigned short* hb  = (unsigned short*)alloc((size_t)NASSIGN * D_FF * 2);
    int*   counts = (int*)alloc(256);
    int*   offs   = (int*)alloc(256);
    int*   ltok   = (int*)alloc((size_t)N_EXP * NTOK * 4);
    float* lw     = (float*)alloc((size_t)N_EXP * NTOK * 4);

    hipMemsetAsync(out, 0, (size_t)out_size * 4, stream);
    hipMemsetAsync(counts, 0, 256, stream);
    cvt_bf16_kernel<<<4096, 256, 0, stream>>>(W1, w1b, N_EXP * D_FF * D_MODEL);
    cvt_bf16_kernel<<<4096, 256, 0, stream>>>(W2, w2b, N_EXP * D_MODEL * D_FF);
    router_kernel<<<NTOK, 64, 0, stream>>>(x, gw, counts, ltok, lw, xb);
    scan_kernel<<<1, 64, 0, stream>>>(counts, offs);
    gemm1_kernel<<<N_EXP * (NTOK / BM) * (D_FF / BN), THREADS, 0, stream>>>(
        xb, w1b, b1, counts, offs, ltok, hb);
    gemm2_kernel<<<N_EXP * (NTOK / BM) * (D_MODEL / BN), THREADS, 0, stream>>>(
        hb, w2b, b2, counts, offs, ltok, lw, out);
}

// Round 11
// 813.110 us; speedup vs baseline: 1.0151x; 1.0057x over previous
//
#include <hip/hip_runtime.h>
#include <hip/hip_bf16.h>
#include <stdint.h>

#define D_MODEL 1024
#define D_FF    4096
#define N_EXP   8
#define TOPK    2
#define NTOK    8192
#define NASSIGN (NTOK*TOPK)

#define BM 128
#define BN 128
#define BK 64
#define THREADS 256

typedef __bf16 bf16_t;
typedef __attribute__((ext_vector_type(8))) bf16_t bf16x8;
typedef __attribute__((ext_vector_type(4))) float f32x4;

__device__ __forceinline__ unsigned short f2bf(float f) {
    bf16_t b = (bf16_t)f;
    return __builtin_bit_cast(unsigned short, b);
}

__device__ __forceinline__ void gload_lds16(const void* g, void* l) {
    __builtin_amdgcn_global_load_lds(
        (const __attribute__((address_space(1))) void*)g,
        (__attribute__((address_space(3))) void*)l, 16, 0, 0);
}

// ---------------- fp32 -> bf16 convert (weights) ----------------
__global__ void cvt_bf16_kernel(const float* __restrict__ in, unsigned short* __restrict__ outp, int n) {
    int stride = gridDim.x * blockDim.x;
    for (int i = blockIdx.x * blockDim.x + threadIdx.x; i < n / 4; i += stride) {
        float4 v = ((const float4*)in)[i];
        ushort4 o;
        o.x = f2bf(v.x); o.y = f2bf(v.y); o.z = f2bf(v.z); o.w = f2bf(v.w);
        ((ushort4*)outp)[i] = o;
    }
}

// ---------------- router (fused: emits x in bf16 + per-token assignment) ----------------
__global__ __launch_bounds__(64) void router_kernel(
        const float* __restrict__ x, const float* __restrict__ gw,
        int* __restrict__ counts, int* __restrict__ ltok,
        int* __restrict__ aep, float* __restrict__ aw,
        unsigned short* __restrict__ xb) {
    int n = blockIdx.x;
    int lane = threadIdx.x;
    const float* xr = x + (size_t)n * D_MODEL;
    unsigned short* xbr = xb + (size_t)n * D_MODEL;
    float acc[N_EXP];
    #pragma unroll
    for (int e = 0; e < N_EXP; e++) acc[e] = 0.f;
    #pragma unroll
    for (int i = 0; i < 4; i++) {
        int j = lane + i * 64;                  // float4 index
        float4 v = ((const float4*)xr)[j];
        ushort4 o;
        o.x = f2bf(v.x); o.y = f2bf(v.y); o.z = f2bf(v.z); o.w = f2bf(v.w);
        ((ushort4*)xbr)[j] = o;
        int d = j * 4;
        #pragma unroll
        for (int e = 0; e < N_EXP; e++) {
            const float* g = gw + e * D_MODEL + d;
            acc[e] += v.x * g[0] + v.y * g[1] + v.z * g[2] + v.w * g[3];
        }
    }
    #pragma unroll
    for (int e = 0; e < N_EXP; e++) {
        #pragma unroll
        for (int off = 32; off > 0; off >>= 1)
            acc[e] += __shfl_down(acc[e], off);
    }
    if (lane == 0) {
        float mx = acc[0];
        #pragma unroll
        for (int e = 1; e < N_EXP; e++) mx = fmaxf(mx, acc[e]);
        float p[N_EXP];
        float s = 0.f;
        #pragma unroll
        for (int e = 0; e < N_EXP; e++) { p[e] = expf(acc[e] - mx); s += p[e]; }
        float inv = 1.f / s;
        #pragma unroll
        for (int e = 0; e < N_EXP; e++) p[e] *= inv;
        int i0 = 0;
        #pragma unroll
        for (int e = 1; e < N_EXP; e++) if (p[e] > p[i0]) i0 = e;
        int i1 = (i0 == 0) ? 1 : 0;
        #pragma unroll
        for (int e = 0; e < N_EXP; e++) if (e != i0 && p[e] > p[i1]) i1 = e;
        float s2 = p[i0] + p[i1] + 1e-9f;
        float w0 = p[i0] / s2, w1 = p[i1] / s2;
        int pos0 = atomicAdd(&counts[i0], 1);
        ltok[i0 * NTOK + pos0] = n;
        int pos1 = atomicAdd(&counts[i1], 1);
        ltok[i1 * NTOK + pos1] = n;
        aep[2 * n]     = (i0 << 16) | pos0;  aw[2 * n]     = w0;
        aep[2 * n + 1] = (i1 << 16) | pos1;  aw[2 * n + 1] = w1;
    }
}

// ---------------- exclusive scan over 8 expert counts ----------------
__global__ void scan_kernel(const int* __restrict__ counts, int* __restrict__ offs) {
    if (threadIdx.x == 0 && blockIdx.x == 0) {
        int s = 0;
        for (int e = 0; e < N_EXP; e++) { offs[e] = s; s += counts[e]; }
    }
}

// ---------------- combine: out[tok] = w0*yb[slot0] + w1*yb[slot1] ----------------
__global__ __launch_bounds__(256) void combine_kernel(
        const float* __restrict__ yb, const int* __restrict__ offs,
        const int* __restrict__ aep, const float* __restrict__ aw,
        float* __restrict__ out) {
    int n = blockIdx.x;
    int t = threadIdx.x;
    int a0 = aep[2 * n], a1 = aep[2 * n + 1];
    float w0 = aw[2 * n], w1 = aw[2 * n + 1];
    int s0 = offs[a0 >> 16] + (a0 & 0xffff);
    int s1 = offs[a1 >> 16] + (a1 & 0xffff);
    float4 v0 = ((const float4*)(yb + (size_t)s0 * D_MODEL))[t];
    float4 v1 = ((const float4*)(yb + (size_t)s1 * D_MODEL))[t];
    float4 r;
    r.x = w0 * v0.x + w1 * v1.x;
    r.y = w0 * v0.y + w1 * v1.y;
    r.z = w0 * v0.z + w1 * v1.z;
    r.w = w0 * v0.w + w1 * v1.w;
    ((float4*)(out + (size_t)n * D_MODEL))[t] = r;
}

// =====================================================================
// r11 = r4/r10 GEMM structure (BK=64 XOR-swizzle conflicts=0, expert->XCD,
// panel-major, single 32KB LDS, syncthreads loop, bounds=(256,4)).
// gemm2 epilogue: NO atomics — writes per-assignment fp32 rows yb[slot]
// (+b2). r10 counters showed the atomic scatter cost +460MB of HBM
// RMW ping-pong under full co-residency (two XCDs hammering each out
// line). Combine pass gathers yb with router-recorded (e,pos,w): fully
// coalesced, no out-memset. yb aliases xb+w1b (dead after gemm1).
// =====================================================================

// GEMM1: h = relu(X_gathered @ W1[e]^T + b1[e])
__global__ __launch_bounds__(THREADS, 4) void gemm1_kernel(
        const unsigned short* __restrict__ xb, const unsigned short* __restrict__ w1b,
        const float* __restrict__ b1,
        const int* __restrict__ counts, const int* __restrict__ offs,
        const int* __restrict__ ltok,
        unsigned short* __restrict__ hb) {
    const int NTM = NTOK / BM;   // 64 (worst case)
    int b = blockIdx.x;
    int e = b & 7;               // expert -> XCD
    int idx = b >> 3;
    int nt = idx / NTM;          // W-panel major: co-resident blocks share nt
    int mt = idx % NTM;
    int cnt = counts[e];
    if (mt * BM >= cnt) return;

    __shared__ __align__(16) unsigned short As[BM * BK];   // 16 KB
    __shared__ __align__(16) unsigned short Bs[BN * BK];   // 16 KB

    int t = threadIdx.x;
    int lane = t & 63, w = t >> 6;     // 4 waves
    int wr = w >> 1, wc = w & 1;       // 2 x 2

    int srow = t >> 3;                       // 0..31
    int schunk = (t & 7) ^ (srow & 7);
    const unsigned short* aptr[4];
    const unsigned short* bptr[4];
    #pragma unroll
    for (int j = 0; j < 4; j++) {
        int rr = srow + j * 32;
        int slot = mt * BM + rr;
        int cs = slot < cnt ? slot : (cnt - 1);
        int tok = ltok[e * NTOK + cs];
        aptr[j] = xb + (size_t)tok * D_MODEL + schunk * 8;
        bptr[j] = w1b + ((size_t)e * D_FF + nt * BN + rr) * D_MODEL + schunk * 8;
    }
    char* As_b = (char*)As;
    char* Bs_b = (char*)Bs;

    int arow_base = wr * 64 + (lane & 15);
    int brow_base = wc * 64 + (lane & 15);
    int ch[2];
    #pragma unroll
    for (int ks = 0; ks < 2; ks++)
        ch[ks] = ((ks * 4 + (lane >> 4)) ^ (lane & 7)) << 4;

    f32x4 acc[4][4];
    #pragma unroll
    for (int m = 0; m < 4; m++)
        #pragma unroll
        for (int n = 0; n < 4; n++)
            acc[m][n] = (f32x4){0.f, 0.f, 0.f, 0.f};

    for (int k0 = 0; k0 < D_MODEL; k0 += BK) {
        #pragma unroll
        for (int j = 0; j < 4; j++) {
            gload_lds16(aptr[j] + k0, As_b + j * 4096 + t * 16);
            gload_lds16(bptr[j] + k0, Bs_b + j * 4096 + t * 16);
        }
        __syncthreads();
        bf16x8 af[2][4], bf[2][4];
        #pragma unroll
        for (int ks = 0; ks < 2; ks++) {
            #pragma unroll
            for (int m = 0; m < 4; m++)
                af[ks][m] = *(const bf16x8*)(As_b + (size_t)(arow_base + m * 16) * 128 + ch[ks]);
            #pragma unroll
            for (int n = 0; n < 4; n++)
                bf[ks][n] = *(const bf16x8*)(Bs_b + (size_t)(brow_base + n * 16) * 128 + ch[ks]);
        }
        #pragma unroll
        for (int ks = 0; ks < 2; ks++)
            #pragma unroll
            for (int m = 0; m < 4; m++)
                #pragma unroll
                for (int n = 0; n < 4; n++)
                    acc[m][n] = __builtin_amdgcn_mfma_f32_16x16x32_bf16(af[ks][m], bf[ks][n], acc[m][n], 0, 0, 0);
        __syncthreads();
    }

    int hbase = offs[e];
    float biasv[4];
    #pragma unroll
    for (int n = 0; n < 4; ++n)
        biasv[n] = b1[e * D_FF + nt * BN + wc * 64 + n * 16 + (lane & 15)];
    #pragma unroll
    for (int m = 0; m < 4; ++m) {
        int s0 = mt * BM + wr * 64 + m * 16 + (lane >> 4) * 4;
        #pragma unroll
        for (int rq = 0; rq < 4; ++rq) {
            int s = s0 + rq;
            if (s < cnt) {
                size_t rowoff = (size_t)(hbase + s) * D_FF + nt * BN + wc * 64 + (lane & 15);
                #pragma unroll
                for (int n = 0; n < 4; ++n) {
                    float v = fmaxf(acc[m][n][rq] + biasv[n], 0.f);
                    hb[rowoff + n * 16] = f2bf(v);
                }
            }
        }
    }
}

// GEMM2: yb[slot] = h[slot] @ W2[e]^T + b2[e]   (plain coalesced stores)
__global__ __launch_bounds__(THREADS, 4) void gemm2_kernel(
        const unsigned short* __restrict__ hb, const unsigned short* __restrict__ w2b,
        const float* __restrict__ b2,
        const int* __restrict__ counts, const int* __restrict__ offs,
        float* __restrict__ yb) {
    const int NTM = NTOK / BM;     // 64
    int b = blockIdx.x;
    int e = b & 7;
    int idx = b >> 3;
    int nt = idx / NTM;
    int mt = idx % NTM;
    int cnt = counts[e];
    if (mt * BM >= cnt) return;
    int hbase = offs[e];

    __shared__ __align__(16) unsigned short As[BM * BK];
    __shared__ __align__(16) unsigned short Bs[BN * BK];

    int t = threadIdx.x;
    int lane = t & 63, w = t >> 6;
    int wr = w >> 1, wc = w & 1;

    int srow = t >> 3;
    int schunk = (t & 7) ^ (srow & 7);
    const unsigned short* aptr[4];
    const unsigned short* bptr[4];
    #pragma unroll
    for (int j = 0; j < 4; j++) {
        int rr = srow + j * 32;
        int slot = mt * BM + rr;
        int cs = slot < cnt ? slot : (cnt - 1);
        aptr[j] = hb + (size_t)(hbase + cs) * D_FF + schunk * 8;
        bptr[j] = w2b + ((size_t)e * D_MODEL + nt * BN + rr) * D_FF + schunk * 8;
    }
    char* As_b = (char*)As;
    char* Bs_b = (char*)Bs;

    int arow_base = wr * 64 + (lane & 15);
    int brow_base = wc * 64 + (lane & 15);
    int ch[2];
    #pragma unroll
    for (int ks = 0; ks < 2; ks++)
        ch[ks] = ((ks * 4 + (lane >> 4)) ^ (lane & 7)) << 4;

    f32x4 acc[4][4];
    #pragma unroll
    for (int m = 0; m < 4; m++)
        #pragma unroll
        for (int n = 0; n < 4; n++)
            acc[m][n] = (f32x4){0.f, 0.f, 0.f, 0.f};

    for (int k0 = 0; k0 < D_FF; k0 += BK) {
        #pragma unroll
        for (int j = 0; j < 4; j++) {
            gload_lds16(aptr[j] + k0, As_b + j * 4096 + t * 16);
            gload_lds16(bptr[j] + k0, Bs_b + j * 4096 + t * 16);
        }
        __syncthreads();
        bf16x8 af[2][4], bf[2][4];
        #pragma unroll
        for (int ks = 0; ks < 2; ks++) {
            #pragma unroll
            for (int m = 0; m < 4; m++)
                af[ks][m] = *(const bf16x8*)(As_b + (size_t)(arow_base + m * 16) * 128 + ch[ks]);
            #pragma unroll
            for (int n = 0; n < 4; n++)
                bf[ks][n] = *(const bf16x8*)(Bs_b + (size_t)(brow_base + n * 16) * 128 + ch[ks]);
        }
        #pragma unroll
        for (int ks = 0; ks < 2; ks++)
            #pragma unroll
            for (int m = 0; m < 4; m++)
                #pragma unroll
                for (int n = 0; n < 4; n++)
                    acc[m][n] = __builtin_amdgcn_mfma_f32_16x16x32_bf16(af[ks][m], bf[ks][n], acc[m][n], 0, 0, 0);
        __syncthreads();
    }

    // epilogue: plain stores of y+b2 into per-assignment rows
    float biasv[4];
    #pragma unroll
    for (int n = 0; n < 4; ++n)
        biasv[n] = b2[e * D_MODEL + nt * BN + wc * 64 + n * 16 + (lane & 15)];
    #pragma unroll
    for (int m = 0; m < 4; ++m) {
        int s0 = mt * BM + wr * 64 + m * 16 + (lane >> 4) * 4;
        #pragma unroll
        for (int rq = 0; rq < 4; ++rq) {
            int s = s0 + rq;
            if (s >= cnt) continue;
            float* yrow = yb + (size_t)(hbase + s) * D_MODEL + nt * BN + wc * 64 + (lane & 15);
            #pragma unroll
            for (int n = 0; n < 4; ++n)
                yrow[n * 16] = acc[m][n][rq] + biasv[n];
        }
    }
}

extern "C" void kernel_launch(void* const* d_in, const int* in_sizes, int n_in,
                              void* d_out, int out_size, void* d_ws, size_t ws_size,
                              hipStream_t stream) {
    const float* x  = (const float*)d_in[0];
    const float* gw = (const float*)d_in[1];
    const float* W1 = (const float*)d_in[2];
    const float* b1 = (const float*)d_in[3];
    const float* W2 = (const float*)d_in[4];
    const float* b2 = (const float*)d_in[5];
    float* out = (float*)d_out;

    char* ws = (char*)d_ws;
    size_t off = 0;
    auto alloc = [&](size_t bytes) -> char* {
        char* p = ws + off;
        off += (bytes + 255) & ~(size_t)255;
        return p;
    };
    unsigned short* xb  = (unsigned short*)alloc((size_t)NTOK * D_MODEL * 2);   // 16 MB
    unsigned short* w1b = (unsigned short*)alloc((size_t)N_EXP * D_FF * D_MODEL * 2); // 64 MB
    unsigned short* w2b = (unsigned short*)alloc((size_t)N_EXP * D_MODEL * D_FF * 2); // 64 MB
    unsigned short* hb  = (unsigned short*)alloc((size_t)NASSIGN * D_FF * 2);   // 134 MB
    int*   counts = (int*)alloc(256);
    int*   offs   = (int*)alloc(256);
    int*   ltok   = (int*)alloc((size_t)N_EXP * NTOK * 4);
    int*   aep    = (int*)alloc((size_t)NASSIGN * 4);
    float* aw     = (float*)alloc((size_t)NASSIGN * 4);
    // yb (16384 x 1024 fp32 = 67 MB) aliases xb+w1b (80 MB, dead after gemm1)
    float* yb = (float*)ws;

    hipMemsetAsync(counts, 0, 256, stream);
    cvt_bf16_kernel<<<4096, 256, 0, stream>>>(W1, w1b, N_EXP * D_FF * D_MODEL);
    cvt_bf16_kernel<<<4096, 256, 0, stream>>>(W2, w2b, N_EXP * D_MODEL * D_FF);
    router_kernel<<<NTOK, 64, 0, stream>>>(x, gw, counts, ltok, aep, aw, xb);
    scan_kernel<<<1, 64, 0, stream>>>(counts, offs);
    gemm1_kernel<<<N_EXP * (NTOK / BM) * (D_FF / BN), THREADS, 0, stream>>>(
        xb, w1b, b1, counts, offs, ltok, hb);
    gemm2_kernel<<<N_EXP * (NTOK / BM) * (D_MODEL / BN), THREADS, 0, stream>>>(
        hb, w2b, b2, counts, offs, yb);
    combine_kernel<<<NTOK, 256, 0, stream>>>(yb, offs, aep, aw, out);
}

// Round 12
// 681.137 us; speedup vs baseline: 1.2118x; 1.1938x over previous
//
#include <hip/hip_runtime.h>
#include <hip/hip_bf16.h>
#include <stdint.h>

#define D_MODEL 1024
#define D_FF    4096
#define N_EXP   8
#define TOPK    2
#define NTOK    8192
#define NASSIGN (NTOK*TOPK)

#define BM 128
#define BN 128
#define BK 64
#define THREADS 256

typedef __bf16 bf16_t;
typedef __attribute__((ext_vector_type(8))) bf16_t bf16x8;
typedef __attribute__((ext_vector_type(4))) float f32x4;

__device__ __forceinline__ unsigned short f2bf(float f) {
    bf16_t b = (bf16_t)f;
    return __builtin_bit_cast(unsigned short, b);
}

__device__ __forceinline__ void gload_lds16(const void* g, void* l) {
    __builtin_amdgcn_global_load_lds(
        (const __attribute__((address_space(1))) void*)g,
        (__attribute__((address_space(3))) void*)l, 16, 0, 0);
}

// ---------------- fp32 -> bf16 convert: W1 and W2 in ONE launch ----------------
__global__ void cvt_both_kernel(const float* __restrict__ W1, unsigned short* __restrict__ o1, int n1,
                                const float* __restrict__ W2, unsigned short* __restrict__ o2, int n2) {
    int stride = gridDim.x * blockDim.x;
    int q1 = n1 / 4, q2 = n2 / 4;
    for (int i = blockIdx.x * blockDim.x + threadIdx.x; i < q1 + q2; i += stride) {
        const float4* src; ushort4* dst; int k;
        if (i < q1) { src = (const float4*)W1; dst = (ushort4*)o1; k = i; }
        else        { src = (const float4*)W2; dst = (ushort4*)o2; k = i - q1; }
        float4 v = src[k];
        ushort4 o;
        o.x = f2bf(v.x); o.y = f2bf(v.y); o.z = f2bf(v.z); o.w = f2bf(v.w);
        dst[k] = o;
    }
}

// ---------------- router (fused: also emits x in bf16) ----------------
__global__ __launch_bounds__(64) void router_kernel(
        const float* __restrict__ x, const float* __restrict__ gw,
        int* __restrict__ counts, int* __restrict__ ltok, float* __restrict__ lw,
        unsigned short* __restrict__ xb) {
    int n = blockIdx.x;
    int lane = threadIdx.x;
    const float* xr = x + (size_t)n * D_MODEL;
    unsigned short* xbr = xb + (size_t)n * D_MODEL;
    float acc[N_EXP];
    #pragma unroll
    for (int e = 0; e < N_EXP; e++) acc[e] = 0.f;
    #pragma unroll
    for (int i = 0; i < 4; i++) {
        int j = lane + i * 64;                  // float4 index
        float4 v = ((const float4*)xr)[j];
        ushort4 o;
        o.x = f2bf(v.x); o.y = f2bf(v.y); o.z = f2bf(v.z); o.w = f2bf(v.w);
        ((ushort4*)xbr)[j] = o;
        int d = j * 4;
        #pragma unroll
        for (int e = 0; e < N_EXP; e++) {
            const float* g = gw + e * D_MODEL + d;
            acc[e] += v.x * g[0] + v.y * g[1] + v.z * g[2] + v.w * g[3];
        }
    }
    #pragma unroll
    for (int e = 0; e < N_EXP; e++) {
        #pragma unroll
        for (int off = 32; off > 0; off >>= 1)
            acc[e] += __shfl_down(acc[e], off);
    }
    if (lane == 0) {
        float mx = acc[0];
        #pragma unroll
        for (int e = 1; e < N_EXP; e++) mx = fmaxf(mx, acc[e]);
        float p[N_EXP];
        float s = 0.f;
        #pragma unroll
        for (int e = 0; e < N_EXP; e++) { p[e] = expf(acc[e] - mx); s += p[e]; }
        float inv = 1.f / s;
        #pragma unroll
        for (int e = 0; e < N_EXP; e++) p[e] *= inv;
        int i0 = 0;
        #pragma unroll
        for (int e = 1; e < N_EXP; e++) if (p[e] > p[i0]) i0 = e;
        int i1 = (i0 == 0) ? 1 : 0;
        #pragma unroll
        for (int e = 0; e < N_EXP; e++) if (e != i0 && p[e] > p[i1]) i1 = e;
        float s2 = p[i0] + p[i1] + 1e-9f;
        float w0 = p[i0] / s2, w1 = p[i1] / s2;
        int pos0 = atomicAdd(&counts[i0], 1);
        ltok[i0 * NTOK + pos0] = n; lw[i0 * NTOK + pos0] = w0;
        int pos1 = atomicAdd(&counts[i1], 1);
        ltok[i1 * NTOK + pos1] = n; lw[i1 * NTOK + pos1] = w1;
    }
}

// ---------------- exclusive scan over 8 expert counts ----------------
__global__ void scan_kernel(const int* __restrict__ counts, int* __restrict__ offs) {
    if (threadIdx.x == 0 && blockIdx.x == 0) {
        int s = 0;
        for (int e = 0; e < N_EXP; e++) { offs[e] = s; s += counts[e]; }
    }
}

// =====================================================================
// r12 = r4 verbatim (measured best: gemm2 225us, FETCH~ideal 200MB,
// conflicts 0): BK=64 XOR-swizzle, single 32KB LDS, syncthreads loop,
// bounds=(256,3) — the residency knee is sharp: 3 blocks/CU keeps L2
// reuse, 4 thrashes it (r10/r11: FETCH 200->435MB regardless of atomic
// vs store epilogue). Atomic scatter epilogue restored (r4-measured
// WRITE 65MB at this residency; combine pass was a wash).
// =====================================================================

// GEMM1: h = relu(X_gathered @ W1[e]^T + b1[e])
__global__ __launch_bounds__(THREADS, 3) void gemm1_kernel(
        const unsigned short* __restrict__ xb, const unsigned short* __restrict__ w1b,
        const float* __restrict__ b1,
        const int* __restrict__ counts, const int* __restrict__ offs,
        const int* __restrict__ ltok,
        unsigned short* __restrict__ hb) {
    const int NTM = NTOK / BM;   // 64 (worst case)
    int b = blockIdx.x;
    int e = b & 7;               // expert -> XCD
    int idx = b >> 3;
    int nt = idx / NTM;          // W-panel major: co-resident blocks share nt
    int mt = idx % NTM;
    int cnt = counts[e];
    if (mt * BM >= cnt) return;

    __shared__ __align__(16) unsigned short As[BM * BK];   // 16 KB
    __shared__ __align__(16) unsigned short Bs[BN * BK];   // 16 KB

    int t = threadIdx.x;
    int lane = t & 63, w = t >> 6;     // 4 waves
    int wr = w >> 1, wc = w & 1;       // 2 x 2

    int srow = t >> 3;                       // 0..31
    int schunk = (t & 7) ^ (srow & 7);
    const unsigned short* aptr[4];
    const unsigned short* bptr[4];
    #pragma unroll
    for (int j = 0; j < 4; j++) {
        int rr = srow + j * 32;
        int slot = mt * BM + rr;
        int cs = slot < cnt ? slot : (cnt - 1);
        int tok = ltok[e * NTOK + cs];
        aptr[j] = xb + (size_t)tok * D_MODEL + schunk * 8;
        bptr[j] = w1b + ((size_t)e * D_FF + nt * BN + rr) * D_MODEL + schunk * 8;
    }
    char* As_b = (char*)As;
    char* Bs_b = (char*)Bs;

    int arow_base = wr * 64 + (lane & 15);
    int brow_base = wc * 64 + (lane & 15);
    int ch[2];
    #pragma unroll
    for (int ks = 0; ks < 2; ks++)
        ch[ks] = ((ks * 4 + (lane >> 4)) ^ (lane & 7)) << 4;

    f32x4 acc[4][4];
    #pragma unroll
    for (int m = 0; m < 4; m++)
        #pragma unroll
        for (int n = 0; n < 4; n++)
            acc[m][n] = (f32x4){0.f, 0.f, 0.f, 0.f};

    for (int k0 = 0; k0 < D_MODEL; k0 += BK) {
        #pragma unroll
        for (int j = 0; j < 4; j++) {
            gload_lds16(aptr[j] + k0, As_b + j * 4096 + t * 16);
            gload_lds16(bptr[j] + k0, Bs_b + j * 4096 + t * 16);
        }
        __syncthreads();
        bf16x8 af[2][4], bf[2][4];
        #pragma unroll
        for (int ks = 0; ks < 2; ks++) {
            #pragma unroll
            for (int m = 0; m < 4; m++)
                af[ks][m] = *(const bf16x8*)(As_b + (size_t)(arow_base + m * 16) * 128 + ch[ks]);
            #pragma unroll
            for (int n = 0; n < 4; n++)
                bf[ks][n] = *(const bf16x8*)(Bs_b + (size_t)(brow_base + n * 16) * 128 + ch[ks]);
        }
        #pragma unroll
        for (int ks = 0; ks < 2; ks++)
            #pragma unroll
            for (int m = 0; m < 4; m++)
                #pragma unroll
                for (int n = 0; n < 4; n++)
                    acc[m][n] = __builtin_amdgcn_mfma_f32_16x16x32_bf16(af[ks][m], bf[ks][n], acc[m][n], 0, 0, 0);
        __syncthreads();
    }

    int hbase = offs[e];
    float biasv[4];
    #pragma unroll
    for (int n = 0; n < 4; ++n)
        biasv[n] = b1[e * D_FF + nt * BN + wc * 64 + n * 16 + (lane & 15)];
    #pragma unroll
    for (int m = 0; m < 4; ++m) {
        int s0 = mt * BM + wr * 64 + m * 16 + (lane >> 4) * 4;
        #pragma unroll
        for (int rq = 0; rq < 4; ++rq) {
            int s = s0 + rq;
            if (s < cnt) {
                size_t rowoff = (size_t)(hbase + s) * D_FF + nt * BN + wc * 64 + (lane & 15);
                #pragma unroll
                for (int n = 0; n < 4; ++n) {
                    float v = fmaxf(acc[m][n][rq] + biasv[n], 0.f);
                    hb[rowoff + n * 16] = f2bf(v);
                }
            }
        }
    }
}

// GEMM2: y = h @ W2[e]^T + b2[e]; weighted atomic scatter to out
__global__ __launch_bounds__(THREADS, 3) void gemm2_kernel(
        const unsigned short* __restrict__ hb, const unsigned short* __restrict__ w2b,
        const float* __restrict__ b2,
        const int* __restrict__ counts, const int* __restrict__ offs,
        const int* __restrict__ ltok, const float* __restrict__ lw,
        float* __restrict__ out) {
    const int NTM = NTOK / BM;     // 64
    int b = blockIdx.x;
    int e = b & 7;
    int idx = b >> 3;
    int nt = idx / NTM;
    int mt = idx % NTM;
    int cnt = counts[e];
    if (mt * BM >= cnt) return;
    int hbase = offs[e];

    __shared__ __align__(16) unsigned short As[BM * BK];
    __shared__ __align__(16) unsigned short Bs[BN * BK];

    int t = threadIdx.x;
    int lane = t & 63, w = t >> 6;
    int wr = w >> 1, wc = w & 1;

    int srow = t >> 3;
    int schunk = (t & 7) ^ (srow & 7);
    const unsigned short* aptr[4];
    const unsigned short* bptr[4];
    #pragma unroll
    for (int j = 0; j < 4; j++) {
        int rr = srow + j * 32;
        int slot = mt * BM + rr;
        int cs = slot < cnt ? slot : (cnt - 1);
        aptr[j] = hb + (size_t)(hbase + cs) * D_FF + schunk * 8;
        bptr[j] = w2b + ((size_t)e * D_MODEL + nt * BN + rr) * D_FF + schunk * 8;
    }
    char* As_b = (char*)As;
    char* Bs_b = (char*)Bs;

    int arow_base = wr * 64 + (lane & 15);
    int brow_base = wc * 64 + (lane & 15);
    int ch[2];
    #pragma unroll
    for (int ks = 0; ks < 2; ks++)
        ch[ks] = ((ks * 4 + (lane >> 4)) ^ (lane & 7)) << 4;

    f32x4 acc[4][4];
    #pragma unroll
    for (int m = 0; m < 4; m++)
        #pragma unroll
        for (int n = 0; n < 4; n++)
            acc[m][n] = (f32x4){0.f, 0.f, 0.f, 0.f};

    for (int k0 = 0; k0 < D_FF; k0 += BK) {
        #pragma unroll
        for (int j = 0; j < 4; j++) {
            gload_lds16(aptr[j] + k0, As_b + j * 4096 + t * 16);
            gload_lds16(bptr[j] + k0, Bs_b + j * 4096 + t * 16);
        }
        __syncthreads();
        bf16x8 af[2][4], bf[2][4];
        #pragma unroll
        for (int ks = 0; ks < 2; ks++) {
            #pragma unroll
            for (int m = 0; m < 4; m++)
                af[ks][m] = *(const bf16x8*)(As_b + (size_t)(arow_base + m * 16) * 128 + ch[ks]);
            #pragma unroll
            for (int n = 0; n < 4; n++)
                bf[ks][n] = *(const bf16x8*)(Bs_b + (size_t)(brow_base + n * 16) * 128 + ch[ks]);
        }
        #pragma unroll
        for (int ks = 0; ks < 2; ks++)
            #pragma unroll
            for (int m = 0; m < 4; m++)
                #pragma unroll
                for (int n = 0; n < 4; n++)
                    acc[m][n] = __builtin_amdgcn_mfma_f32_16x16x32_bf16(af[ks][m], bf[ks][n], acc[m][n], 0, 0, 0);
        __syncthreads();
    }

    int lbase = e * NTOK;
    float biasv[4];
    #pragma unroll
    for (int n = 0; n < 4; ++n)
        biasv[n] = b2[e * D_MODEL + nt * BN + wc * 64 + n * 16 + (lane & 15)];
    #pragma unroll
    for (int m = 0; m < 4; ++m) {
        int s0 = mt * BM + wr * 64 + m * 16 + (lane >> 4) * 4;
        #pragma unroll
        for (int rq = 0; rq < 4; ++rq) {
            int s = s0 + rq;
            if (s >= cnt) continue;
            int tok = ltok[lbase + s];
            float wgt = lw[lbase + s];
            float* orow = out + (size_t)tok * D_MODEL + nt * BN + wc * 64 + (lane & 15);
            #pragma unroll
            for (int n = 0; n < 4; ++n)
                atomicAdd(orow + n * 16, wgt * (acc[m][n][rq] + biasv[n]));
        }
    }
}

extern "C" void kernel_launch(void* const* d_in, const int* in_sizes, int n_in,
                              void* d_out, int out_size, void* d_ws, size_t ws_size,
                              hipStream_t stream) {
    const float* x  = (const float*)d_in[0];
    const float* gw = (const float*)d_in[1];
    const float* W1 = (const float*)d_in[2];
    const float* b1 = (const float*)d_in[3];
    const float* W2 = (const float*)d_in[4];
    const float* b2 = (const float*)d_in[5];
    float* out = (float*)d_out;

    char* ws = (char*)d_ws;
    size_t off = 0;
    auto alloc = [&](size_t bytes) -> char* {
        char* p = ws + off;
        off += (bytes + 255) & ~(size_t)255;
        return p;
    };
    unsigned short* xb  = (unsigned short*)alloc((size_t)NTOK * D_MODEL * 2);
    unsigned short* w1b = (unsigned short*)alloc((size_t)N_EXP * D_FF * D_MODEL * 2);
    unsigned short* w2b = (unsigned short*)alloc((size_t)N_EXP * D_MODEL * D_FF * 2);
    unsigned short* hb  = (unsigned short*)alloc((size_t)NASSIGN * D_FF * 2);
    int*   counts = (int*)alloc(256);
    int*   offs   = (int*)alloc(256);
    int*   ltok   = (int*)alloc((size_t)N_EXP * NTOK * 4);
    float* lw     = (float*)alloc((size_t)N_EXP * NTOK * 4);

    hipMemsetAsync(out, 0, (size_t)out_size * 4, stream);
    hipMemsetAsync(counts, 0, 256, stream);
    cvt_both_kernel<<<8192, 256, 0, stream>>>(
        W1, w1b, N_EXP * D_FF * D_MODEL, W2, w2b, N_EXP * D_MODEL * D_FF);
    router_kernel<<<NTOK, 64, 0, stream>>>(x, gw, counts, ltok, lw, xb);
    scan_kernel<<<1, 64, 0, stream>>>(counts, offs);
    gemm1_kernel<<<N_EXP * (NTOK / BM) * (D_FF / BN), THREADS, 0, stream>>>(
        xb, w1b, b1, counts, offs, ltok, hb);
    gemm2_kernel<<<N_EXP * (NTOK / BM) * (D_MODEL / BN), THREADS, 0, stream>>>(
        hb, w2b, b2, counts, offs, ltok, lw, out);
}